// Round 6
// baseline (145.326 us; speedup 1.0000x reference)
//
#include <hip/hip_runtime.h>
#include <cmath>

#define FIN 256
#define FQK 256
#define SCALING 0.0625f  // FQK^-0.5 = 1/16
#define ASTRIDE 264      // f16 elems per LDS row: 528 B (b128-aligned, 2-way banks max)

typedef _Float16 f16_t;
typedef f16_t f16x8 __attribute__((ext_vector_type(8)));
typedef f16_t f16x2 __attribute__((ext_vector_type(2)));
typedef float f32x4 __attribute__((ext_vector_type(4)));

// fp32 -> fp16x8 (RNE via native cast)
__device__ __forceinline__ f16x8 cvt8h(float4 a, float4 b) {
    f16x8 r;
    r[0] = (f16_t)a.x; r[1] = (f16_t)a.y; r[2] = (f16_t)a.z; r[3] = (f16_t)a.w;
    r[4] = (f16_t)b.x; r[5] = (f16_t)b.y; r[6] = (f16_t)b.z; r[7] = (f16_t)b.w;
    return r;
}

// v_dot2_f32_f16 when available; exact scalar fallback otherwise
__device__ __forceinline__ float fdot2f(f16x2 a, f16x2 b, float c) {
#if __has_builtin(__builtin_amdgcn_fdot2)
    return __builtin_amdgcn_fdot2(a, b, c, false);
#else
    return c + (float)a[0] * (float)b[0] + (float)a[1] * (float)b[1];
#endif
}

union H16 { uint4 u; f16x2 h[4]; };
__device__ __forceinline__ float dot16(uint4 ya, uint4 xa, float acc) {
    H16 A; A.u = ya;
    H16 X; X.u = xa;
#pragma unroll
    for (int i = 0; i < 4; ++i) acc = fdot2f(A.h[i], X.h[i], acc);
    return acc;
}

// ---------------------------------------------------------------------------
// Kernel 1 (fused): blocks [0,FIN): MbF (B-fragment-swizzled M matrix, fp16)
//   M[f][k] = SCALING * sum_c W[c][f] * W[256+c][k]
//   flat = (((k>>5)*16 + (f>>4))*64 + ((k>>3)&3)*16 + (f&15))*8 + (k&7)
// blocks [FIN, FIN+segBlocks): seg[n] = lower_bound(src, n).
// ---------------------------------------------------------------------------
__global__ __launch_bounds__(256) void m_seg_kernel(const float* __restrict__ W,
                                                    f16_t* __restrict__ MbF,
                                                    const int* __restrict__ src,
                                                    int* __restrict__ seg, int N, int E) {
    const int b = blockIdx.x;
    if (b < FIN) {
        const int f = b;
        const int k = threadIdx.x;
        const float* __restrict__ Wq = W;              // block-uniform loads
        const float* __restrict__ Wk = W + FQK * FIN;  // coalesced loads
        float acc = 0.f;
#pragma unroll 8
        for (int c = 0; c < FQK; ++c)
            acc += Wq[c * FIN + f] * Wk[c * FIN + k];
        const int ft  = f >> 4, m16 = f & 15;
        const int kcI = k >> 5, q = (k >> 3) & 3, e = k & 7;
        MbF[(size_t)(((kcI * 16 + ft) * 64 + q * 16 + m16) * 8 + e)] =
            (f16_t)(acc * SCALING);
    } else {
        const int n = (b - FIN) * 256 + threadIdx.x;
        if (n > N) return;
        int lo = 0, hi = E;
        while (lo < hi) {
            const int mid = (lo + hi) >> 1;
            if (src[mid] < n) lo = mid + 1; else hi = mid;
        }
        seg[n] = lo;
    }
}

// ---------------------------------------------------------------------------
// Kernel 2: y[n][f] = sum_k x[n][k] * M[f][k], fp16 MFMA (16x16x32).
// 16 rows/block -> 1251 blocks (4.9/CU). Stage writes BOTH sA (LDS) and xh
// (global fp16 copy of x, coalesced) from the same registers. B-fragments
// coalesced from swizzled MbF (L2-hot). Epilogue via LDS transpose.
// ---------------------------------------------------------------------------
__global__ __launch_bounds__(256) void gemm_y_kernel(const float* __restrict__ x,
                                                     const f16_t* __restrict__ MbF,
                                                     f16_t* __restrict__ y,
                                                     f16_t* __restrict__ xh, int N) {
    __shared__ f16_t sA[16 * ASTRIDE];

    const int t    = threadIdx.x;
    const int wv   = t >> 6;
    const int lane = t & 63;
    const int q    = lane >> 4;    // quad 0..3 -> k-offset q*8
    const int m16  = lane & 15;
    const int n0   = blockIdx.x * 16;
    const int f0   = wv * 64;

    // ---- stage A + xh: pass p -> row p*8 + (t>>5), cols (t&31)*8..+8
    {
        const int rsub = t >> 5;          // 0..7
        const int col  = (t & 31) * 8;
#pragma unroll
        for (int p = 0; p < 2; ++p) {
            const int r  = p * 8 + rsub;
            const int n  = n0 + r;
            const int nc = n < N ? n : N - 1;
            const float* __restrict__ xp = x + (size_t)nc * FIN + col;
            const float4 a = *(const float4*)(xp);
            const float4 b = *(const float4*)(xp + 4);
            const f16x8 v = cvt8h(a, b);
            *(f16x8*)&sA[r * ASTRIDE + col] = v;
            if (n < N) *(f16x8*)(xh + (size_t)n * FIN + col) = v;
        }
    }
    __syncthreads();

    f32x4 acc[4] = {};   // [f-tile]

#pragma unroll
    for (int kc = 0; kc < FIN; kc += 32) {
        const f16x8 af = *(const f16x8*)&sA[m16 * ASTRIDE + kc + q * 8];
        const f16_t* __restrict__ bp =
            MbF + (size_t)(((kc >> 5) * 16 + (f0 >> 4)) * 64 + lane) * 8;
#pragma unroll
        for (int ft = 0; ft < 4; ++ft) {
            union { uint4 u; f16x8 v; } bu;
            bu.u = *(const uint4*)(bp + ft * 512);
            acc[ft] = __builtin_amdgcn_mfma_f32_16x16x32_f16(af, bu.v, acc[ft], 0, 0, 0);
        }
    }

    // ---- epilogue: transpose through LDS for packed stores
    __syncthreads();   // all A-reads done; safe to overwrite sA
#pragma unroll
    for (int ft = 0; ft < 4; ++ft)
#pragma unroll
        for (int r = 0; r < 4; ++r)
            sA[(q * 4 + r) * ASTRIDE + f0 + ft * 16 + m16] = (f16_t)acc[ft][r];
    __syncthreads();

    {
        const int row = t >> 4;           // 0..15
        const int c   = (t & 15) * 16;    // f16-element col
        const int n   = n0 + row;
        if (n < N) {
            const uint4 v0 = *(const uint4*)&sA[row * ASTRIDE + c];
            const uint4 v1 = *(const uint4*)&sA[row * ASTRIDE + c + 8];
            *(uint4*)(y + (size_t)n * FIN + c)     = v0;
            *(uint4*)(y + (size_t)n * FIN + c + 8) = v1;
        }
    }
}

// ---------------------------------------------------------------------------
// Kernel 3: FLAT edge loop. Each wave owns a contiguous span of edges;
// 8-lane groups (g=edge slot 0..7, j=64B slice); 8 edges/iter; 2-deep
// prefetch of BOTH y[dest] (random gather) and xh[src] (sorted -> L1-hot).
// No per-node restarts, perfect balance. Writes ex=exp(dot) to out[e].
// All gathered indices clamped (rocprof replay re-poisons inputs).
// ---------------------------------------------------------------------------
__global__ __launch_bounds__(256) void edge_dot_kernel(const f16_t* __restrict__ xh,
                                                       const f16_t* __restrict__ y,
                                                       const int* __restrict__ src,
                                                       const int* __restrict__ dest,
                                                       float* __restrict__ out,
                                                       int N, int E, int span) {
    const int w    = threadIdx.x >> 6;
    const int lane = threadIdx.x & 63;
    const int g    = lane >> 3;    // edge slot 0..7
    const int j    = lane & 7;     // 64B slice of the row

    const int base = (blockIdx.x * 4 + w) * span;
    if (base >= E) return;
    const int end = min(base + span, E);

#define ECLAMP(d, L) ((unsigned)(d) < (unsigned)(L) ? (d) : 0)

#define EISSUE(Y0, Y1, Y2, Y3, X0, X1, X2, X3, e, valid)                       \
    if (valid) {                                                               \
        const int d_ = ECLAMP(dest[e], N);                                     \
        const int s_ = ECLAMP(src[e], N);                                      \
        const uint4* __restrict__ yr = (const uint4*)(y + (size_t)d_ * FIN) + j * 4;  \
        const uint4* __restrict__ xr = (const uint4*)(xh + (size_t)s_ * FIN) + j * 4; \
        Y0 = yr[0]; Y1 = yr[1]; Y2 = yr[2]; Y3 = yr[3];                        \
        X0 = xr[0]; X1 = xr[1]; X2 = xr[2]; X3 = xr[3];                        \
    }

#define ECONSUME(Y0, Y1, Y2, Y3, X0, X1, X2, X3, e, valid)                     \
    if (valid) {                                                               \
        float a_ = 0.f;                                                        \
        a_ = dot16(Y0, X0, a_);                                                \
        a_ = dot16(Y1, X1, a_);                                                \
        a_ = dot16(Y2, X2, a_);                                                \
        a_ = dot16(Y3, X3, a_);                                                \
        a_ += __shfl_xor(a_, 1, 64);                                           \
        a_ += __shfl_xor(a_, 2, 64);                                           \
        a_ += __shfl_xor(a_, 4, 64);                                           \
        if (j == 0) out[e] = __expf(a_);                                       \
    }

    uint4 A0, A1, A2, A3, AX0, AX1, AX2, AX3;
    uint4 B0, B1, B2, B3, BX0, BX1, BX2, BX3;

    int  eA = base + g;
    bool vA = eA < end;
    EISSUE(A0, A1, A2, A3, AX0, AX1, AX2, AX3, eA, vA);

    const int nit = (end - base + 7) >> 3;
    for (int it = 0; it < nit; it += 2) {
        const int eB = base + (it + 1) * 8 + g;
        const bool vB = eB < end;
        EISSUE(B0, B1, B2, B3, BX0, BX1, BX2, BX3, eB, vB);
        ECONSUME(A0, A1, A2, A3, AX0, AX1, AX2, AX3, eA, vA);
        eA = base + (it + 2) * 8 + g;
        vA = eA < end;
        EISSUE(A0, A1, A2, A3, AX0, AX1, AX2, AX3, eA, vA);
        ECONSUME(B0, B1, B2, B3, BX0, BX1, BX2, BX3, eB, vB);
    }

#undef EISSUE
#undef ECONSUME
#undef ECLAMP
}

// ---------------------------------------------------------------------------
// Kernel 4: segment softmax-normalize in place. 8 lanes per node: pass 1
// sums ex over the node's edge range (L2-hot), pass 2 scales by 1/sum.
// ---------------------------------------------------------------------------
__global__ __launch_bounds__(256) void segnorm_kernel(float* __restrict__ out,
                                                      const int* __restrict__ seg,
                                                      int N, int E) {
    const int n = blockIdx.x * 32 + (threadIdx.x >> 3);
    const int j = threadIdx.x & 7;
    if (n >= N) return;

    int s0 = seg[n], s1 = seg[n + 1];
    s0 = min(max(s0, 0), E);                 // replay-poison clamps
    s1 = min(max(s1, 0), E);
    if (s1 <= s0) return;

    float sum = 0.f;
    for (int i = s0 + j; i < s1; i += 8) sum += out[i];
    sum += __shfl_xor(sum, 1, 64);
    sum += __shfl_xor(sum, 2, 64);
    sum += __shfl_xor(sum, 4, 64);
    const float inv = 1.0f / sum;

    for (int i = s0 + j; i < s1; i += 8) out[i] *= inv;
}

// ---------------------------------------------------------------------------
extern "C" void kernel_launch(void* const* d_in, const int* in_sizes, int n_in,
                              void* d_out, int out_size, void* d_ws, size_t ws_size,
                              hipStream_t stream) {
    const float* x  = (const float*)d_in[0];
    const int*   ei = (const int*)d_in[1];
    const float* W  = (const float*)d_in[2];
    float* out = (float*)d_out;

    const int N = in_sizes[0] / FIN;
    const int E = in_sizes[1] / 2;

    // workspace layout (all fp16 tables 16B-aligned)
    f16_t* MbF = (f16_t*)d_ws;                        // 256*256 fp16 (swizzled)
    f16_t* y   = MbF + (size_t)FIN * FIN;             // N*256 fp16
    f16_t* xh  = y + (size_t)N * FIN;                 // N*256 fp16
    int*   seg = (int*)(xh + (size_t)N * FIN);        // N+1

    const int segBlocks = (N + 256) / 256;            // covers n = 0..N
    m_seg_kernel<<<FIN + segBlocks, 256, 0, stream>>>(W, MbF, ei, seg, N, E);

    gemm_y_kernel<<<(N + 15) / 16, 256, 0, stream>>>(x, MbF, y, xh, N);

    const int neBlocks = 1024;                        // 4096 waves
    const int nwaves   = neBlocks * 4;
    const int span     = ((E + nwaves - 1) / nwaves + 7) & ~7;
    edge_dot_kernel<<<neBlocks, 256, 0, stream>>>(xh, y, ei, ei + E, out, N, E, span);

    segnorm_kernel<<<(N + 31) / 32, 256, 0, stream>>>(out, seg, N, E);
}

// Round 7
// 133.553 us; speedup vs baseline: 1.0882x; 1.0882x over previous
//
#include <hip/hip_runtime.h>
#include <cmath>

#define FIN 256
#define FQK 256
#define SCALING 0.0625f  // FQK^-0.5 = 1/16
#define MAX_SEG 256
#define ASTRIDE 264      // f16 elems per LDS row: 528 B (b128-aligned, 2-way banks max)

typedef _Float16 f16_t;
typedef f16_t f16x8 __attribute__((ext_vector_type(8)));
typedef f16_t f16x2 __attribute__((ext_vector_type(2)));
typedef float f32x4 __attribute__((ext_vector_type(4)));

// fp32 -> fp16x8 (RNE via native cast)
__device__ __forceinline__ f16x8 cvt8h(float4 a, float4 b) {
    f16x8 r;
    r[0] = (f16_t)a.x; r[1] = (f16_t)a.y; r[2] = (f16_t)a.z; r[3] = (f16_t)a.w;
    r[4] = (f16_t)b.x; r[5] = (f16_t)b.y; r[6] = (f16_t)b.z; r[7] = (f16_t)b.w;
    return r;
}

// v_dot2_f32_f16 when available; exact scalar fallback otherwise
__device__ __forceinline__ float fdot2f(f16x2 a, f16x2 b, float c) {
#if __has_builtin(__builtin_amdgcn_fdot2)
    return __builtin_amdgcn_fdot2(a, b, c, false);
#else
    return c + (float)a[0] * (float)b[0] + (float)a[1] * (float)b[1];
#endif
}

union H16 { uint4 u; f16x2 h[4]; };
__device__ __forceinline__ float dot16(uint4 ya, uint4 xa, float acc) {
    H16 A; A.u = ya;
    H16 X; X.u = xa;
#pragma unroll
    for (int i = 0; i < 4; ++i) acc = fdot2f(A.h[i], X.h[i], acc);
    return acc;
}

// ---------------------------------------------------------------------------
// Kernel 1 (fused): blocks [0,FIN): MbF (B-fragment-swizzled M matrix, fp16)
//   M[f][k] = SCALING * sum_c W[c][f] * W[256+c][k]
//   flat = (((k>>5)*16 + (f>>4))*64 + ((k>>3)&3)*16 + (f&15))*8 + (k&7)
// blocks [FIN, FIN+segBlocks): seg[n] = lower_bound(src, n).
// ---------------------------------------------------------------------------
__global__ __launch_bounds__(256) void m_seg_kernel(const float* __restrict__ W,
                                                    f16_t* __restrict__ MbF,
                                                    const int* __restrict__ src,
                                                    int* __restrict__ seg, int N, int E) {
    const int b = blockIdx.x;
    if (b < FIN) {
        const int f = b;
        const int k = threadIdx.x;
        const float* __restrict__ Wq = W;              // block-uniform loads
        const float* __restrict__ Wk = W + FQK * FIN;  // coalesced loads
        float acc = 0.f;
#pragma unroll 8
        for (int c = 0; c < FQK; ++c)
            acc += Wq[c * FIN + f] * Wk[c * FIN + k];
        const int ft  = f >> 4, m16 = f & 15;
        const int kcI = k >> 5, q = (k >> 3) & 3, e = k & 7;
        MbF[(size_t)(((kcI * 16 + ft) * 64 + q * 16 + m16) * 8 + e)] =
            (f16_t)(acc * SCALING);
    } else {
        const int n = (b - FIN) * 256 + threadIdx.x;
        if (n > N) return;
        int lo = 0, hi = E;
        while (lo < hi) {
            const int mid = (lo + hi) >> 1;
            if (src[mid] < n) lo = mid + 1; else hi = mid;
        }
        seg[n] = lo;
    }
}

// ---------------------------------------------------------------------------
// Kernel 2: y[n][f] = sum_k x[n][k] * M[f][k], fp16 MFMA (16x16x32).
// 16 rows/block -> 1251 blocks (4.9/CU). Stage writes BOTH sA (LDS) and xh
// (global fp16 copy of x, coalesced) from the same registers. B-fragments
// coalesced from swizzled MbF (L2-hot). Epilogue via LDS transpose.
// ---------------------------------------------------------------------------
__global__ __launch_bounds__(256) void gemm_y_kernel(const float* __restrict__ x,
                                                     const f16_t* __restrict__ MbF,
                                                     f16_t* __restrict__ y,
                                                     f16_t* __restrict__ xh, int N) {
    __shared__ f16_t sA[16 * ASTRIDE];

    const int t    = threadIdx.x;
    const int wv   = t >> 6;
    const int lane = t & 63;
    const int q    = lane >> 4;    // quad 0..3 -> k-offset q*8
    const int m16  = lane & 15;
    const int n0   = blockIdx.x * 16;
    const int f0   = wv * 64;

    // ---- stage A + xh: pass p -> row p*8 + (t>>5), cols (t&31)*8..+8
    {
        const int rsub = t >> 5;          // 0..7
        const int col  = (t & 31) * 8;
#pragma unroll
        for (int p = 0; p < 2; ++p) {
            const int r  = p * 8 + rsub;
            const int n  = n0 + r;
            const int nc = n < N ? n : N - 1;
            const float* __restrict__ xp = x + (size_t)nc * FIN + col;
            const float4 a = *(const float4*)(xp);
            const float4 b = *(const float4*)(xp + 4);
            const f16x8 v = cvt8h(a, b);
            *(f16x8*)&sA[r * ASTRIDE + col] = v;
            if (n < N) *(f16x8*)(xh + (size_t)n * FIN + col) = v;
        }
    }
    __syncthreads();

    f32x4 acc[4] = {};   // [f-tile]

#pragma unroll
    for (int kc = 0; kc < FIN; kc += 32) {
        const f16x8 af = *(const f16x8*)&sA[m16 * ASTRIDE + kc + q * 8];
        const f16_t* __restrict__ bp =
            MbF + (size_t)(((kc >> 5) * 16 + (f0 >> 4)) * 64 + lane) * 8;
#pragma unroll
        for (int ft = 0; ft < 4; ++ft) {
            union { uint4 u; f16x8 v; } bu;
            bu.u = *(const uint4*)(bp + ft * 512);
            acc[ft] = __builtin_amdgcn_mfma_f32_16x16x32_f16(af, bu.v, acc[ft], 0, 0, 0);
        }
    }

    // ---- epilogue: transpose through LDS for packed stores
    __syncthreads();   // all A-reads done; safe to overwrite sA
#pragma unroll
    for (int ft = 0; ft < 4; ++ft)
#pragma unroll
        for (int r = 0; r < 4; ++r)
            sA[(q * 4 + r) * ASTRIDE + f0 + ft * 16 + m16] = (f16_t)acc[ft][r];
    __syncthreads();

    {
        const int row = t >> 4;           // 0..15
        const int c   = (t & 15) * 16;    // f16-element col
        const int n   = n0 + row;
        if (n < N) {
            const uint4 v0 = *(const uint4*)&sA[row * ASTRIDE + c];
            const uint4 v1 = *(const uint4*)&sA[row * ASTRIDE + c + 8];
            *(uint4*)(y + (size_t)n * FIN + c)     = v0;
            *(uint4*)(y + (size_t)n * FIN + c + 8) = v1;
        }
    }
}

// ---------------------------------------------------------------------------
// Kernel 3: node-centric persistent waves (2048 blocks x 4 waves = 8192
// streams = 32 waves/CU nominal; was 16/CU). 8-lane groups (g=edge slot,
// j=64B slice); x row hoisted to regs per node; 2-deep y-gather pipeline,
// x2 unrolled. dest indices prefetched ONE PHASE ahead of their gathers
// (breaks the index->gather dependent hop). fp16 fdot2 dot.
// All gathered indices clamped (rocprof replay re-poisons inputs).
// ---------------------------------------------------------------------------
__global__ __launch_bounds__(256) void node_edge_kernel(const f16_t* __restrict__ xh,
                                                        const f16_t* __restrict__ y,
                                                        const int* __restrict__ dest,
                                                        const int* __restrict__ seg,
                                                        float* __restrict__ out,
                                                        int N, int E, int nwaves) {
    __shared__ float exlds[4][MAX_SEG];

    const int w    = threadIdx.x >> 6;
    const int lane = threadIdx.x & 63;
    const int g    = lane >> 3;    // edge slot 0..7
    const int j    = lane & 7;     // 64B slice of the row

#define DCLAMP(d) ((unsigned)(d) < (unsigned)N ? (d) : 0)

// issue gathers for one stage, taking the prefetched dest VALUE
#define GISSUE(B0, B1, B2, B3, dval, valid)                                    \
    if (valid) {                                                               \
        const int d_ = DCLAMP(dval);                                           \
        const uint4* __restrict__ yr = (const uint4*)(y + (size_t)d_ * FIN) + j * 4; \
        B0 = yr[0]; B1 = yr[1]; B2 = yr[2]; B3 = yr[3];                        \
    }

#define CONSUME(B0, B1, B2, B3, idx, valid)                                    \
    if (valid) {                                                               \
        float a_ = 0.f;                                                        \
        a_ = dot16(B0, X0, a_);                                                \
        a_ = dot16(B1, X1, a_);                                                \
        a_ = dot16(B2, X2, a_);                                                \
        a_ = dot16(B3, X3, a_);                                                \
        a_ += __shfl_xor(a_, 1, 64);                                           \
        a_ += __shfl_xor(a_, 2, 64);                                           \
        a_ += __shfl_xor(a_, 4, 64);                                           \
        const float ex = __expf(a_);                                           \
        sum += ex;                                                             \
        if (j == 0 && (idx) < MAX_SEG) exlds[w][idx] = ex;                     \
    }

    for (int n = blockIdx.x * 4 + w; n < N; n += nwaves) {
        int s0 = seg[n], s1 = seg[n + 1];
        s0 = min(max(s0, 0), E);                     // replay-poison clamps
        s1 = min(max(s1, 0), E);
        const int cnt = s1 - s0;
        if (cnt <= 0) continue;

        // xh[n] slice for this lane: elements j*32 .. +32 (fp16)
        const uint4* __restrict__ xp = (const uint4*)(xh + (size_t)n * FIN + j * 32);
        const uint4 X0 = xp[0], X1 = xp[1], X2 = xp[2], X3 = xp[3];

        float sum = 0.f;
        const int nit = (cnt + 7) >> 3;

        uint4 A0, A1, A2, A3, B0, B1, B2, B3;

        bool vA = g < cnt;
        int  dA = vA ? dest[s0 + g] : 0;             // idx for stage 0
        GISSUE(A0, A1, A2, A3, dA, vA);
        bool vBn = (8 + g) < cnt;                    // idx for stage 1, a phase early
        int  dB  = vBn ? dest[s0 + 8 + g] : 0;

        for (int it = 0; it < nit; it += 2) {
            const int  iB = (it + 1) * 8 + g;        // stage it+1
            const bool vB = iB < cnt;
            GISSUE(B0, B1, B2, B3, dB, vB);
            const int  iA2 = (it + 2) * 8 + g;       // prefetch idx for stage it+2
            const bool vA2 = iA2 < cnt;
            dA = vA2 ? dest[s0 + iA2] : 0;
            CONSUME(A0, A1, A2, A3, it * 8 + g, vA);
            GISSUE(A0, A1, A2, A3, dA, vA2);
            const int  iB3 = (it + 3) * 8 + g;       // prefetch idx for stage it+3
            const bool vB3 = iB3 < cnt;
            dB = vB3 ? dest[s0 + iB3] : 0;
            CONSUME(B0, B1, B2, B3, iB, vB);
            vA = vA2;
        }

        // 8 groups hold identical partial sums internally; combine groups
        sum += __shfl_xor(sum, 8, 64);
        sum += __shfl_xor(sum, 16, 64);
        sum += __shfl_xor(sum, 32, 64);
        const float inv = 1.0f / sum;

        const int lim = cnt < MAX_SEG ? cnt : MAX_SEG;
        for (int i = lane; i < lim; i += 64)
            out[s0 + i] = exlds[w][i] * inv;
    }

#undef GISSUE
#undef CONSUME
#undef DCLAMP
}

// ---------------------------------------------------------------------------
extern "C" void kernel_launch(void* const* d_in, const int* in_sizes, int n_in,
                              void* d_out, int out_size, void* d_ws, size_t ws_size,
                              hipStream_t stream) {
    const float* x  = (const float*)d_in[0];
    const int*   ei = (const int*)d_in[1];
    const float* W  = (const float*)d_in[2];
    float* out = (float*)d_out;

    const int N = in_sizes[0] / FIN;
    const int E = in_sizes[1] / 2;

    // workspace layout (all fp16 tables 16B-aligned)
    f16_t* MbF = (f16_t*)d_ws;                        // 256*256 fp16 (swizzled)
    f16_t* y   = MbF + (size_t)FIN * FIN;             // N*256 fp16
    f16_t* xh  = y + (size_t)N * FIN;                 // N*256 fp16
    int*   seg = (int*)(xh + (size_t)N * FIN);        // N+1

    const int segBlocks = (N + 256) / 256;            // covers n = 0..N
    m_seg_kernel<<<FIN + segBlocks, 256, 0, stream>>>(W, MbF, ei, seg, N, E);

    gemm_y_kernel<<<(N + 15) / 16, 256, 0, stream>>>(x, MbF, y, xh, N);

    const int neBlocks = 2048;                        // 8192 waves = 32/CU nominal
    node_edge_kernel<<<neBlocks, 256, 0, stream>>>(xh, y, ei + E, seg, out,
                                                   N, E, neBlocks * 4);
}

// Round 8
// 130.900 us; speedup vs baseline: 1.1102x; 1.0203x over previous
//
#include <hip/hip_runtime.h>
#include <cmath>

#define FIN 256
#define FQK 256
#define SCALING 0.0625f  // FQK^-0.5 = 1/16
#define MAX_SEG 256
#define ASTRIDE 264      // f16 elems per LDS row: 528 B (b128-aligned, 2-way banks max)

typedef _Float16 f16_t;
typedef f16_t f16x8 __attribute__((ext_vector_type(8)));
typedef f16_t f16x2 __attribute__((ext_vector_type(2)));
typedef float f32x4 __attribute__((ext_vector_type(4)));

// fp32 -> fp16x8 (RNE via native cast)
__device__ __forceinline__ f16x8 cvt8h(float4 a, float4 b) {
    f16x8 r;
    r[0] = (f16_t)a.x; r[1] = (f16_t)a.y; r[2] = (f16_t)a.z; r[3] = (f16_t)a.w;
    r[4] = (f16_t)b.x; r[5] = (f16_t)b.y; r[6] = (f16_t)b.z; r[7] = (f16_t)b.w;
    return r;
}

// v_dot2_f32_f16 when available; exact scalar fallback otherwise
__device__ __forceinline__ float fdot2f(f16x2 a, f16x2 b, float c) {
#if __has_builtin(__builtin_amdgcn_fdot2)
    return __builtin_amdgcn_fdot2(a, b, c, false);
#else
    return c + (float)a[0] * (float)b[0] + (float)a[1] * (float)b[1];
#endif
}

union H16 { uint4 u; f16x2 h[4]; };
__device__ __forceinline__ float dot16(uint4 ya, uint4 xa, float acc) {
    H16 A; A.u = ya;
    H16 X; X.u = xa;
#pragma unroll
    for (int i = 0; i < 4; ++i) acc = fdot2f(A.h[i], X.h[i], acc);
    return acc;
}

// ---------------------------------------------------------------------------
// Kernel 1 (fused): blocks [0,FIN): MbF (B-fragment-swizzled M matrix, fp16)
//   M[f][k] = SCALING * sum_c W[c][f] * W[256+c][k]
//   flat = (((k>>5)*16 + (f>>4))*64 + ((k>>3)&3)*16 + (f&15))*8 + (k&7)
// blocks [FIN, FIN+segBlocks): seg[n] = lower_bound(src, n).
// ---------------------------------------------------------------------------
__global__ __launch_bounds__(256) void m_seg_kernel(const float* __restrict__ W,
                                                    f16_t* __restrict__ MbF,
                                                    const int* __restrict__ src,
                                                    int* __restrict__ seg, int N, int E) {
    const int b = blockIdx.x;
    if (b < FIN) {
        const int f = b;
        const int k = threadIdx.x;
        const float* __restrict__ Wq = W;              // block-uniform loads
        const float* __restrict__ Wk = W + FQK * FIN;  // coalesced loads
        float acc = 0.f;
#pragma unroll 8
        for (int c = 0; c < FQK; ++c)
            acc += Wq[c * FIN + f] * Wk[c * FIN + k];
        const int ft  = f >> 4, m16 = f & 15;
        const int kcI = k >> 5, q = (k >> 3) & 3, e = k & 7;
        MbF[(size_t)(((kcI * 16 + ft) * 64 + q * 16 + m16) * 8 + e)] =
            (f16_t)(acc * SCALING);
    } else {
        const int n = (b - FIN) * 256 + threadIdx.x;
        if (n > N) return;
        int lo = 0, hi = E;
        while (lo < hi) {
            const int mid = (lo + hi) >> 1;
            if (src[mid] < n) lo = mid + 1; else hi = mid;
        }
        seg[n] = lo;
    }
}

// ---------------------------------------------------------------------------
// Kernel 2: y[n][f] = sum_k x[n][k] * M[f][k], fp16 MFMA (16x16x32).
// 16 rows/block -> 1251 blocks (4.9/CU). Stage writes BOTH sA (LDS) and xh
// (global fp16 copy of x, coalesced) from the same registers. B-fragments
// coalesced from swizzled MbF (L2-hot). Epilogue via LDS transpose.
// ---------------------------------------------------------------------------
__global__ __launch_bounds__(256) void gemm_y_kernel(const float* __restrict__ x,
                                                     const f16_t* __restrict__ MbF,
                                                     f16_t* __restrict__ y,
                                                     f16_t* __restrict__ xh, int N) {
    __shared__ f16_t sA[16 * ASTRIDE];

    const int t    = threadIdx.x;
    const int wv   = t >> 6;
    const int lane = t & 63;
    const int q    = lane >> 4;    // quad 0..3 -> k-offset q*8
    const int m16  = lane & 15;
    const int n0   = blockIdx.x * 16;
    const int f0   = wv * 64;

    // ---- stage A + xh: pass p -> row p*8 + (t>>5), cols (t&31)*8..+8
    {
        const int rsub = t >> 5;          // 0..7
        const int col  = (t & 31) * 8;
#pragma unroll
        for (int p = 0; p < 2; ++p) {
            const int r  = p * 8 + rsub;
            const int n  = n0 + r;
            const int nc = n < N ? n : N - 1;
            const float* __restrict__ xp = x + (size_t)nc * FIN + col;
            const float4 a = *(const float4*)(xp);
            const float4 b = *(const float4*)(xp + 4);
            const f16x8 v = cvt8h(a, b);
            *(f16x8*)&sA[r * ASTRIDE + col] = v;
            if (n < N) *(f16x8*)(xh + (size_t)n * FIN + col) = v;
        }
    }
    __syncthreads();

    f32x4 acc[4] = {};   // [f-tile]

#pragma unroll
    for (int kc = 0; kc < FIN; kc += 32) {
        const f16x8 af = *(const f16x8*)&sA[m16 * ASTRIDE + kc + q * 8];
        const f16_t* __restrict__ bp =
            MbF + (size_t)(((kc >> 5) * 16 + (f0 >> 4)) * 64 + lane) * 8;
#pragma unroll
        for (int ft = 0; ft < 4; ++ft) {
            union { uint4 u; f16x8 v; } bu;
            bu.u = *(const uint4*)(bp + ft * 512);
            acc[ft] = __builtin_amdgcn_mfma_f32_16x16x32_f16(af, bu.v, acc[ft], 0, 0, 0);
        }
    }

    // ---- epilogue: transpose through LDS for packed stores
    __syncthreads();   // all A-reads done; safe to overwrite sA
#pragma unroll
    for (int ft = 0; ft < 4; ++ft)
#pragma unroll
        for (int r = 0; r < 4; ++r)
            sA[(q * 4 + r) * ASTRIDE + f0 + ft * 16 + m16] = (f16_t)acc[ft][r];
    __syncthreads();

    {
        const int row = t >> 4;           // 0..15
        const int c   = (t & 15) * 16;    // f16-element col
        const int n   = n0 + row;
        if (n < N) {
            const uint4 v0 = *(const uint4*)&sA[row * ASTRIDE + c];
            const uint4 v1 = *(const uint4*)&sA[row * ASTRIDE + c + 8];
            *(uint4*)(y + (size_t)n * FIN + c)     = v0;
            *(uint4*)(y + (size_t)n * FIN + c + 8) = v1;
        }
    }
}

// ---------------------------------------------------------------------------
// Kernel 3: node-centric persistent waves (2048 blocks x 4 waves). 8-lane
// groups (g=edge slot, j). TRANSACTION-COALESCED gather layout: within each
// uint4 load instruction, the 8 lanes of a group read 8 CONSECUTIVE uint4s
// (128 B = 2 full cache lines, 4 lanes/line) instead of stride-64 (8 partial
// lines). Requests/edge drop 32 -> 8; dot pairing unchanged because the x
// slice uses the identical mapping. 2-deep y-gather pipeline, dest indices
// prefetched one phase ahead. All gathered indices clamped (replay poison).
// ---------------------------------------------------------------------------
__global__ __launch_bounds__(256) void node_edge_kernel(const f16_t* __restrict__ xh,
                                                        const f16_t* __restrict__ y,
                                                        const int* __restrict__ dest,
                                                        const int* __restrict__ seg,
                                                        float* __restrict__ out,
                                                        int N, int E, int nwaves) {
    __shared__ float exlds[4][MAX_SEG];

    const int w    = threadIdx.x >> 6;
    const int lane = threadIdx.x & 63;
    const int g    = lane >> 3;    // edge slot 0..7
    const int j    = lane & 7;     // 16B sub-slice within each 128B chunk

#define DCLAMP(d) ((unsigned)(d) < (unsigned)N ? (d) : 0)

// issue gathers for one stage, taking the prefetched dest VALUE.
// lane j reads uint4 index u*8+j -> group covers 128 B contiguous per instr.
#define GISSUE(B0, B1, B2, B3, dval, valid)                                    \
    if (valid) {                                                               \
        const int d_ = DCLAMP(dval);                                           \
        const uint4* __restrict__ yr = (const uint4*)(y + (size_t)d_ * FIN);   \
        B0 = yr[j]; B1 = yr[8 + j]; B2 = yr[16 + j]; B3 = yr[24 + j];          \
    }

#define CONSUME(B0, B1, B2, B3, idx, valid)                                    \
    if (valid) {                                                               \
        float a_ = 0.f;                                                        \
        a_ = dot16(B0, X0, a_);                                                \
        a_ = dot16(B1, X1, a_);                                                \
        a_ = dot16(B2, X2, a_);                                                \
        a_ = dot16(B3, X3, a_);                                                \
        a_ += __shfl_xor(a_, 1, 64);                                           \
        a_ += __shfl_xor(a_, 2, 64);                                           \
        a_ += __shfl_xor(a_, 4, 64);                                           \
        const float ex = __expf(a_);                                           \
        sum += ex;                                                             \
        if (j == 0 && (idx) < MAX_SEG) exlds[w][idx] = ex;                     \
    }

    for (int n = blockIdx.x * 4 + w; n < N; n += nwaves) {
        int s0 = seg[n], s1 = seg[n + 1];
        s0 = min(max(s0, 0), E);                     // replay-poison clamps
        s1 = min(max(s1, 0), E);
        const int cnt = s1 - s0;
        if (cnt <= 0) continue;

        // xh[n] slices with the SAME mapping as the gather (features match)
        const uint4* __restrict__ xp = (const uint4*)(xh + (size_t)n * FIN);
        const uint4 X0 = xp[j], X1 = xp[8 + j], X2 = xp[16 + j], X3 = xp[24 + j];

        float sum = 0.f;
        const int nit = (cnt + 7) >> 3;

        uint4 A0, A1, A2, A3, B0, B1, B2, B3;

        bool vA = g < cnt;
        int  dA = vA ? dest[s0 + g] : 0;             // idx for stage 0
        GISSUE(A0, A1, A2, A3, dA, vA);
        bool vBn = (8 + g) < cnt;                    // idx for stage 1, a phase early
        int  dB  = vBn ? dest[s0 + 8 + g] : 0;

        for (int it = 0; it < nit; it += 2) {
            const int  iB = (it + 1) * 8 + g;        // stage it+1
            const bool vB = iB < cnt;
            GISSUE(B0, B1, B2, B3, dB, vB);
            const int  iA2 = (it + 2) * 8 + g;       // prefetch idx for stage it+2
            const bool vA2 = iA2 < cnt;
            dA = vA2 ? dest[s0 + iA2] : 0;
            CONSUME(A0, A1, A2, A3, it * 8 + g, vA);
            GISSUE(A0, A1, A2, A3, dA, vA2);
            const int  iB3 = (it + 3) * 8 + g;       // prefetch idx for stage it+3
            const bool vB3 = iB3 < cnt;
            dB = vB3 ? dest[s0 + iB3] : 0;
            CONSUME(B0, B1, B2, B3, iB, vB);
            vA = vA2;
        }

        // 8 groups hold identical partial sums internally; combine groups
        sum += __shfl_xor(sum, 8, 64);
        sum += __shfl_xor(sum, 16, 64);
        sum += __shfl_xor(sum, 32, 64);
        const float inv = 1.0f / sum;

        const int lim = cnt < MAX_SEG ? cnt : MAX_SEG;
        for (int i = lane; i < lim; i += 64)
            out[s0 + i] = exlds[w][i] * inv;
    }

#undef GISSUE
#undef CONSUME
#undef DCLAMP
}

// ---------------------------------------------------------------------------
extern "C" void kernel_launch(void* const* d_in, const int* in_sizes, int n_in,
                              void* d_out, int out_size, void* d_ws, size_t ws_size,
                              hipStream_t stream) {
    const float* x  = (const float*)d_in[0];
    const int*   ei = (const int*)d_in[1];
    const float* W  = (const float*)d_in[2];
    float* out = (float*)d_out;

    const int N = in_sizes[0] / FIN;
    const int E = in_sizes[1] / 2;

    // workspace layout (all fp16 tables 16B-aligned)
    f16_t* MbF = (f16_t*)d_ws;                        // 256*256 fp16 (swizzled)
    f16_t* y   = MbF + (size_t)FIN * FIN;             // N*256 fp16
    f16_t* xh  = y + (size_t)N * FIN;                 // N*256 fp16
    int*   seg = (int*)(xh + (size_t)N * FIN);        // N+1

    const int segBlocks = (N + 256) / 256;            // covers n = 0..N
    m_seg_kernel<<<FIN + segBlocks, 256, 0, stream>>>(W, MbF, ei, seg, N, E);

    gemm_y_kernel<<<(N + 15) / 16, 256, 0, stream>>>(x, MbF, y, xh, N);

    const int neBlocks = 2048;                        // 8192 waves = 32/CU nominal
    node_edge_kernel<<<neBlocks, 256, 0, stream>>>(xh, y, ei + E, seg, out,
                                                   N, E, neBlocks * 4);
}